// Round 2
// baseline (1080.073 us; speedup 1.0000x reference)
//
#include <hip/hip_runtime.h>

#define Bn 4
#define Sn 4096
#define Dn 1024
#define En 8
#define Cn 1024
#define Fn 2048
#define Mn (Bn * Cn) // 4096 rows per expert (all batches)

typedef __bf16 bf16x8 __attribute__((ext_vector_type(8)));
typedef float f32x4 __attribute__((ext_vector_type(4)));

// async global->LDS, 16B per lane, linear LDS dest (wave-uniform base + lane*16)
#define GLOAD16(gsrc, ldst)                                                    \
  __builtin_amdgcn_global_load_lds(                                            \
      (const __attribute__((address_space(1))) void*)(gsrc),                   \
      (__attribute__((address_space(3))) void*)(ldst), 16, 0, 0)

// ---- transpose + cast: in[e][K][N] f32  ->  out[e][N][K] bf16 ----
__global__ __launch_bounds__(256) void tcast_kernel(
    const float* __restrict__ in, __bf16* __restrict__ out, int K, int N) {
  __shared__ float t[32][33];
  const int e = blockIdx.z;
  const float* src = in + (size_t)e * K * N;
  __bf16* dst = out + (size_t)e * K * N;
  const int n0 = blockIdx.x << 5, k0 = blockIdx.y << 5;
  const int tx = threadIdx.x & 31, ty = threadIdx.x >> 5;
#pragma unroll
  for (int i = 0; i < 4; ++i)
    t[ty + i * 8][tx] = src[(size_t)(k0 + ty + i * 8) * N + (n0 + tx)];
  __syncthreads();
#pragma unroll
  for (int i = 0; i < 4; ++i)
    dst[(size_t)(n0 + ty + i * 8) * K + (k0 + tx)] = (__bf16)t[tx][ty + i * 8];
}

// ---- fused gather + GEMM(w1) + GEMM(w2) + SwiGLU(+ew) -> Hb bf16 [E][Mn][Fn]
// 128x128 tile, BK=32, 4 waves (2x2), A fp32 staged by global_load_lds with
// per-lane gathered+swizzled source addresses; B1/B2 bf16 likewise.
__global__ __launch_bounds__(256) void gemm12_kernel(
    const float* __restrict__ x, const int* __restrict__ tok,
    const float* __restrict__ ew, const __bf16* __restrict__ w1T,
    const __bf16* __restrict__ w2T, __bf16* __restrict__ Hb) {
  __shared__ __align__(16) float As[2][128 * 32];      // 16KB x2
  __shared__ __align__(16) __bf16 B1s[2][128 * 32];    // 8KB x2
  __shared__ __align__(16) __bf16 B2s[2][128 * 32];    // 8KB x2

  const int tid = threadIdx.x;
  const int lane = tid & 63, w = tid >> 6;
  const int wm = w >> 1, wn = w & 1;

  // bijective XCD swizzle: 4096 blocks, XCD k gets [512k, 512k+512) = expert k
  const int sx = (blockIdx.x & 7) * 512 + (blockIdx.x >> 3);
  const int e = sx >> 9;
  const int nt = (sx >> 5) & 15;
  const int mt = sx & 31;
  const int b = mt >> 3;

  // ---- staging source pointers (advance 32 elems / K-step) ----
  // A: 16 slots of 1KB; wave w -> slots w+4i. slot s: row = s*8 + (lane>>3),
  //    16B-block jb = lane&7, swizzled jb^(row&7) = (lane&7)^(lane>>3).
  const int aSwz = ((lane & 7) ^ (lane >> 3)) << 2; // element offset
  const float* pA[4];
#pragma unroll
  for (int i = 0; i < 4; ++i) {
    int row = (w + 4 * i) * 8 + (lane >> 3);
    int t = tok[((size_t)b * En + e) * Cn + ((mt * 128 + row) & (Cn - 1))];
    pA[i] = x + ((size_t)b * Sn + t) * Dn + aSwz;
  }
  // B: 8 slots of 1KB; wave w -> slots w, w+4. slot s: row = s*16 + (lane>>2),
  //    jb = lane&3, swizzled jb ^ ((row>>1)&3) = (lane&3)^((lane>>3)&3).
  const int bSwz = ((lane & 3) ^ ((lane >> 3) & 3)) << 3; // element offset
  const __bf16 *pB1[2], *pB2[2];
#pragma unroll
  for (int i = 0; i < 2; ++i) {
    int row = (w + 4 * i) * 16 + (lane >> 2);
    size_t ro = ((size_t)e * Fn + nt * 128 + row) * Dn + bSwz;
    pB1[i] = w1T + ro;
    pB2[i] = w2T + ro;
  }

  f32x4 acc1[4][4], acc2[4][4];
  const f32x4 z4 = {0.f, 0.f, 0.f, 0.f};
#pragma unroll
  for (int i = 0; i < 4; ++i)
#pragma unroll
    for (int j = 0; j < 4; ++j) {
      acc1[i][j] = z4;
      acc2[i][j] = z4;
    }

  auto stage = [&](int buf) {
#pragma unroll
    for (int i = 0; i < 4; ++i) {
      GLOAD16(pA[i], &As[buf][(w + 4 * i) * 256]);
      pA[i] += 32;
    }
#pragma unroll
    for (int i = 0; i < 2; ++i) {
      GLOAD16(pB1[i], &B1s[buf][(w + 4 * i) * 512]);
      pB1[i] += 32;
      GLOAD16(pB2[i], &B2s[buf][(w + 4 * i) * 512]);
      pB2[i] += 32;
    }
  };

  const int rr = lane & 15, kb = lane >> 4; // frag k-elems [kb*8, kb*8+8)
  auto compute = [&](int buf) {
    bf16x8 a8[4], b18[4], b28[4];
#pragma unroll
    for (int fm = 0; fm < 4; ++fm) {
      const int R = wm * 64 + fm * 16 + rr;
      const int jb0 = (2 * kb) ^ (R & 7);
      const int jb1 = (2 * kb + 1) ^ (R & 7);
      f32x4 lo = *(const f32x4*)&As[buf][R * 32 + jb0 * 4];
      f32x4 hi = *(const f32x4*)&As[buf][R * 32 + jb1 * 4];
      bf16x8 a;
      a[0] = (__bf16)lo[0]; a[1] = (__bf16)lo[1];
      a[2] = (__bf16)lo[2]; a[3] = (__bf16)lo[3];
      a[4] = (__bf16)hi[0]; a[5] = (__bf16)hi[1];
      a[6] = (__bf16)hi[2]; a[7] = (__bf16)hi[3];
      a8[fm] = a;
    }
#pragma unroll
    for (int fn = 0; fn < 4; ++fn) {
      const int R = wn * 64 + fn * 16 + rr;
      const int jb = kb ^ ((R >> 1) & 3);
      b18[fn] = *(const bf16x8*)&B1s[buf][R * 32 + jb * 8];
      b28[fn] = *(const bf16x8*)&B2s[buf][R * 32 + jb * 8];
    }
#pragma unroll
    for (int fm = 0; fm < 4; ++fm)
#pragma unroll
      for (int fn = 0; fn < 4; ++fn) {
        acc1[fm][fn] = __builtin_amdgcn_mfma_f32_16x16x32_bf16(
            a8[fm], b18[fn], acc1[fm][fn], 0, 0, 0);
        acc2[fm][fn] = __builtin_amdgcn_mfma_f32_16x16x32_bf16(
            a8[fm], b28[fn], acc2[fm][fn], 0, 0, 0);
      }
  };

  stage(0);
  __syncthreads();
  int cur = 0;
#pragma unroll 1
  for (int kt = 0; kt < 32; ++kt) {
    if (kt + 1 < 32) stage(cur ^ 1);
    compute(cur);
    __syncthreads();
    cur ^= 1;
  }

  // epilogue: h = silu(g) * v * ew, store bf16
  const int m0 = mt * 128 + wm * 64;
  __bf16* hOut = Hb + ((size_t)e * Mn + m0) * Fn + nt * 128 + wn * 64;
  const size_t ewBase = ((size_t)b * En + e) * Cn;
  const int rb = (lane >> 4) << 2, cb = lane & 15;
#pragma unroll
  for (int fm = 0; fm < 4; ++fm)
#pragma unroll
    for (int j = 0; j < 4; ++j) {
      const int rloc = fm * 16 + rb + j;
      const float wgt = ew[ewBase + ((m0 + rloc) & (Cn - 1))];
#pragma unroll
      for (int fn = 0; fn < 4; ++fn) {
        float g = acc1[fm][fn][j];
        float v = acc2[fm][fn][j];
        float h = (g / (1.f + __expf(-g))) * v * wgt;
        hOut[(size_t)rloc * Fn + fn * 16 + cb] = (__bf16)h;
      }
    }
}

// ---- GEMM3: Hb x w3T -> atomic scatter-add (ew already folded into Hb) ----
__global__ __launch_bounds__(256) void gemm3_kernel(
    const __bf16* __restrict__ Hb, const __bf16* __restrict__ w3T,
    const int* __restrict__ tok, float* __restrict__ out) {
  __shared__ __align__(16) __bf16 As[2][128 * 32];
  __shared__ __align__(16) __bf16 Bs[2][128 * 32];

  const int tid = threadIdx.x;
  const int lane = tid & 63, w = tid >> 6;
  const int wm = w >> 1, wn = w & 1;

  // 2048 blocks: XCD k gets [256k, 256k+256) = expert k
  const int sx = (blockIdx.x & 7) * 256 + (blockIdx.x >> 3);
  const int e = sx >> 8;
  const int nt = (sx >> 5) & 7;
  const int mt = sx & 31;

  const int bSwz = ((lane & 3) ^ ((lane >> 3) & 3)) << 3;
  const __bf16 *pA[2], *pB[2];
#pragma unroll
  for (int i = 0; i < 2; ++i) {
    int row = (w + 4 * i) * 16 + (lane >> 2);
    pA[i] = Hb + ((size_t)e * Mn + mt * 128 + row) * Fn + bSwz;
    pB[i] = w3T + ((size_t)e * Dn + nt * 128 + row) * Fn + bSwz;
  }

  f32x4 acc[4][4];
  const f32x4 z4 = {0.f, 0.f, 0.f, 0.f};
#pragma unroll
  for (int i = 0; i < 4; ++i)
#pragma unroll
    for (int j = 0; j < 4; ++j) acc[i][j] = z4;

  auto stage = [&](int buf) {
#pragma unroll
    for (int i = 0; i < 2; ++i) {
      GLOAD16(pA[i], &As[buf][(w + 4 * i) * 512]);
      pA[i] += 32;
      GLOAD16(pB[i], &Bs[buf][(w + 4 * i) * 512]);
      pB[i] += 32;
    }
  };

  const int rr = lane & 15, kb = lane >> 4;
  auto compute = [&](int buf) {
    bf16x8 a8[4], b8[4];
#pragma unroll
    for (int f = 0; f < 4; ++f) {
      const int Ra = wm * 64 + f * 16 + rr;
      a8[f] = *(const bf16x8*)&As[buf][Ra * 32 + (kb ^ ((Ra >> 1) & 3)) * 8];
      const int Rb = wn * 64 + f * 16 + rr;
      b8[f] = *(const bf16x8*)&Bs[buf][Rb * 32 + (kb ^ ((Rb >> 1) & 3)) * 8];
    }
#pragma unroll
    for (int fm = 0; fm < 4; ++fm)
#pragma unroll
      for (int fn = 0; fn < 4; ++fn)
        acc[fm][fn] = __builtin_amdgcn_mfma_f32_16x16x32_bf16(
            a8[fm], b8[fn], acc[fm][fn], 0, 0, 0);
  };

  stage(0);
  __syncthreads();
  int cur = 0;
#pragma unroll 1
  for (int kt = 0; kt < 64; ++kt) { // K = Fn = 2048
    if (kt + 1 < 64) stage(cur ^ 1);
    compute(cur);
    __syncthreads();
    cur ^= 1;
  }

  // epilogue: atomic scatter-add into out[b, tok, :]
  const int b = mt >> 3;
  const int m0 = mt * 128 + wm * 64;
  const int colBase = nt * 128 + wn * 64 + (lane & 15);
  const int rb = (lane >> 4) << 2;
#pragma unroll
  for (int fm = 0; fm < 4; ++fm) {
#pragma unroll
    for (int j = 0; j < 4; ++j) {
      const int m = m0 + fm * 16 + rb + j;
      const int c = m & (Cn - 1);
      const int t = tok[((size_t)b * En + e) * Cn + c];
      float* orow = out + ((size_t)b * Sn + t) * Dn + colBase;
#pragma unroll
      for (int fn = 0; fn < 4; ++fn)
        atomicAdd(orow + fn * 16, acc[fm][fn][j]);
    }
  }
}

extern "C" void kernel_launch(void* const* d_in, const int* in_sizes, int n_in,
                              void* d_out, int out_size, void* d_ws,
                              size_t ws_size, hipStream_t stream) {
  const float* x = (const float*)d_in[0];
  const float* ew = (const float*)d_in[1];
  const int* tok = (const int*)d_in[2];
  const float* w1 = (const float*)d_in[3];
  const float* w2 = (const float*)d_in[4];
  const float* w3 = (const float*)d_in[5];
  float* out = (float*)d_out;

  const size_t wE = (size_t)En * Dn * Fn; // 16,777,216 elems per weight
  __bf16* w1T = (__bf16*)d_ws;
  __bf16* w2T = w1T + wE;
  __bf16* w3T = w2T + wE;
  __bf16* Hb = w3T + wE;
  const size_t need = (3 * wE + (size_t)En * Mn * Fn) * sizeof(__bf16);
  if (ws_size < need) return; // fail loudly (output stays poisoned)

  (void)hipMemsetAsync(d_out, 0, (size_t)Bn * Sn * Dn * sizeof(float), stream);

  tcast_kernel<<<dim3(Fn / 32, Dn / 32, En), 256, 0, stream>>>(w1, w1T, Dn, Fn);
  tcast_kernel<<<dim3(Fn / 32, Dn / 32, En), 256, 0, stream>>>(w2, w2T, Dn, Fn);
  tcast_kernel<<<dim3(Dn / 32, Fn / 32, En), 256, 0, stream>>>(w3, w3T, Fn, Dn);
  gemm12_kernel<<<dim3(4096), 256, 0, stream>>>(x, tok, ew, w1T, w2T, Hb);
  gemm3_kernel<<<dim3(2048), 256, 0, stream>>>(Hb, w3T, tok, out);
}

// Round 3
// 918.562 us; speedup vs baseline: 1.1758x; 1.1758x over previous
//
#include <hip/hip_runtime.h>

#define Bn 4
#define Sn 4096
#define Dn 1024
#define En 8
#define Cn 1024
#define Fn 2048
#define Mn (Bn * Cn) // 4096 rows per expert (all batches)

typedef __bf16 bf16x4 __attribute__((ext_vector_type(4)));
typedef __bf16 bf16x8 __attribute__((ext_vector_type(8)));
typedef float f32x4 __attribute__((ext_vector_type(4)));

// async global->LDS, 16B per lane, linear LDS dest (wave-uniform base + lane*16)
#define GLOAD16(gsrc, ldst)                                                    \
  __builtin_amdgcn_global_load_lds(                                            \
      (const __attribute__((address_space(1))) void*)(gsrc),                   \
      (__attribute__((address_space(3))) void*)(ldst), 16, 0, 0)

// ---- transpose + cast: in[e][K][N] f32  ->  out[e][N][K] bf16 ----
__global__ __launch_bounds__(256) void tcast_kernel(
    const float* __restrict__ in, __bf16* __restrict__ out, int K, int N) {
  __shared__ float t[32][33];
  const int e = blockIdx.z;
  const float* src = in + (size_t)e * K * N;
  __bf16* dst = out + (size_t)e * K * N;
  const int n0 = blockIdx.x << 5, k0 = blockIdx.y << 5;
  const int tx = threadIdx.x & 31, ty = threadIdx.x >> 5;
#pragma unroll
  for (int i = 0; i < 4; ++i)
    t[ty + i * 8][tx] = src[(size_t)(k0 + ty + i * 8) * N + (n0 + tx)];
  __syncthreads();
#pragma unroll
  for (int i = 0; i < 4; ++i)
    dst[(size_t)(n0 + ty + i * 8) * K + (k0 + tx)] = (__bf16)t[tx][ty + i * 8];
}

// ---- gather + cast: Xg[e][m][d] = bf16(x[b(m)][tok[b,e,c(m)]][d]) ----
__global__ __launch_bounds__(256) void gather_cast_kernel(
    const float* __restrict__ x, const int* __restrict__ tok,
    __bf16* __restrict__ Xg) {
  const int gid = blockIdx.x * 4 + (threadIdx.x >> 6); // row in [0, En*Mn)
  const int lane = threadIdx.x & 63;
  const int e = gid >> 12, m = gid & 4095, b = m >> 10, c = m & 1023;
  const int t = tok[((size_t)b * En + e) * Cn + c];
  const float* src = x + ((size_t)b * Sn + t) * Dn;
  __bf16* dst = Xg + (size_t)gid * Dn;
#pragma unroll
  for (int i = 0; i < 4; ++i) {
    f32x4 v = *(const f32x4*)(src + i * 256 + lane * 4);
    bf16x4 o;
    o[0] = (__bf16)v[0];
    o[1] = (__bf16)v[1];
    o[2] = (__bf16)v[2];
    o[3] = (__bf16)v[3];
    *(bf16x4*)(dst + i * 256 + lane * 4) = o;
  }
}

// ---- GEMM(w1) + GEMM(w2) + SwiGLU(+ew) -> Hbh bf16 [4][Mn][Fn] ----
// 128x128 tile, BK=32, 4 waves (2x2). All tiles bf16 via global_load_lds,
// swizzle applied on the per-lane global SOURCE address (rule 21).
__global__ __launch_bounds__(256) void gemm12_kernel(
    const __bf16* __restrict__ Xg, const float* __restrict__ ew,
    const __bf16* __restrict__ w1T, const __bf16* __restrict__ w2T,
    __bf16* __restrict__ Hbh, int e0) {
  __shared__ __align__(16) __bf16 As[2][128 * 32];  // 8KB x2
  __shared__ __align__(16) __bf16 B1s[2][128 * 32];
  __shared__ __align__(16) __bf16 B2s[2][128 * 32];

  const int tid = threadIdx.x;
  const int lane = tid & 63, w = tid >> 6;
  const int wm = w >> 1, wn = w & 1;

  const int eLoc = blockIdx.y, e = e0 + eLoc;
  const int nt = blockIdx.x >> 5; // F/128 = 16
  const int mt = blockIdx.x & 31; // M/128 = 32
  const int b = mt >> 3;

  // staging: tile [128 rows][32 k] bf16; 8 slots of 1KB (16 rows each);
  // wave w -> slots {w, w+4}. lane: row = s*16 + (lane>>2), 16B-block
  // jb = lane&3, source pre-swizzled jb ^ ((row>>1)&3) = jb ^ ((lane>>3)&3).
  const int bSwz = ((lane & 3) ^ ((lane >> 3) & 3)) << 3; // element offset
  const __bf16 *pA[2], *pB1[2], *pB2[2];
#pragma unroll
  for (int i = 0; i < 2; ++i) {
    const int row = (w + 4 * i) * 16 + (lane >> 2);
    pA[i] = Xg + ((size_t)e * Mn + mt * 128 + row) * Dn + bSwz;
    const size_t ro = ((size_t)e * Fn + nt * 128 + row) * Dn + bSwz;
    pB1[i] = w1T + ro;
    pB2[i] = w2T + ro;
  }

  f32x4 acc1[4][4], acc2[4][4];
  const f32x4 z4 = {0.f, 0.f, 0.f, 0.f};
#pragma unroll
  for (int i = 0; i < 4; ++i)
#pragma unroll
    for (int j = 0; j < 4; ++j) {
      acc1[i][j] = z4;
      acc2[i][j] = z4;
    }

  auto stage = [&](int buf) {
#pragma unroll
    for (int i = 0; i < 2; ++i) {
      GLOAD16(pA[i], &As[buf][(w + 4 * i) * 512]);
      pA[i] += 32;
      GLOAD16(pB1[i], &B1s[buf][(w + 4 * i) * 512]);
      pB1[i] += 32;
      GLOAD16(pB2[i], &B2s[buf][(w + 4 * i) * 512]);
      pB2[i] += 32;
    }
  };

  const int rr = lane & 15, kb = lane >> 4; // frag k-elems [kb*8, kb*8+8)
  auto compute = [&](int buf) {
    bf16x8 a8[4], b18[4], b28[4];
#pragma unroll
    for (int f = 0; f < 4; ++f) {
      const int Ra = wm * 64 + f * 16 + rr;
      a8[f] = *(const bf16x8*)&As[buf][Ra * 32 + (kb ^ ((Ra >> 1) & 3)) * 8];
      const int Rb = wn * 64 + f * 16 + rr;
      b18[f] = *(const bf16x8*)&B1s[buf][Rb * 32 + (kb ^ ((Rb >> 1) & 3)) * 8];
      b28[f] = *(const bf16x8*)&B2s[buf][Rb * 32 + (kb ^ ((Rb >> 1) & 3)) * 8];
    }
#pragma unroll
    for (int fm = 0; fm < 4; ++fm)
#pragma unroll
      for (int fn = 0; fn < 4; ++fn) {
        acc1[fm][fn] = __builtin_amdgcn_mfma_f32_16x16x32_bf16(
            a8[fm], b18[fn], acc1[fm][fn], 0, 0, 0);
        acc2[fm][fn] = __builtin_amdgcn_mfma_f32_16x16x32_bf16(
            a8[fm], b28[fn], acc2[fm][fn], 0, 0, 0);
      }
  };

  stage(0);
  __syncthreads();
  int cur = 0;
#pragma unroll 1
  for (int kt = 0; kt < 32; ++kt) {
    if (kt + 1 < 32) stage(cur ^ 1);
    compute(cur);
    __syncthreads();
    cur ^= 1;
  }

  // epilogue: h = silu(g) * v * ew, store bf16
  const int m0 = mt * 128 + wm * 64;
  __bf16* hOut = Hbh + ((size_t)eLoc * Mn + m0) * Fn + nt * 128 + wn * 64;
  const size_t ewBase = ((size_t)b * En + e) * Cn;
  const int rb = (lane >> 4) << 2, cb = lane & 15;
#pragma unroll
  for (int fm = 0; fm < 4; ++fm)
#pragma unroll
    for (int j = 0; j < 4; ++j) {
      const int rloc = fm * 16 + rb + j;
      const float wgt = ew[ewBase + ((m0 + rloc) & (Cn - 1))];
#pragma unroll
      for (int fn = 0; fn < 4; ++fn) {
        float g = acc1[fm][fn][j];
        float v = acc2[fm][fn][j];
        float h = (g / (1.f + __expf(-g))) * v * wgt;
        hOut[(size_t)rloc * Fn + fn * 16 + cb] = (__bf16)h;
      }
    }
}

// ---- GEMM3: Hbh x w3T -> atomic scatter-add (ew folded into Hbh) ----
__global__ __launch_bounds__(256) void gemm3_kernel(
    const __bf16* __restrict__ Hbh, const __bf16* __restrict__ w3T,
    const int* __restrict__ tok, float* __restrict__ out, int e0) {
  __shared__ __align__(16) __bf16 As[2][128 * 32];
  __shared__ __align__(16) __bf16 Bs[2][128 * 32];

  const int tid = threadIdx.x;
  const int lane = tid & 63, w = tid >> 6;
  const int wm = w >> 1, wn = w & 1;

  const int eLoc = blockIdx.y, e = e0 + eLoc;
  const int nt = blockIdx.x >> 5; // D/128 = 8
  const int mt = blockIdx.x & 31; // M/128 = 32

  const int bSwz = ((lane & 3) ^ ((lane >> 3) & 3)) << 3;
  const __bf16 *pA[2], *pB[2];
#pragma unroll
  for (int i = 0; i < 2; ++i) {
    const int row = (w + 4 * i) * 16 + (lane >> 2);
    pA[i] = Hbh + ((size_t)eLoc * Mn + mt * 128 + row) * Fn + bSwz;
    pB[i] = w3T + ((size_t)e * Dn + nt * 128 + row) * Fn + bSwz;
  }

  f32x4 acc[4][4];
  const f32x4 z4 = {0.f, 0.f, 0.f, 0.f};
#pragma unroll
  for (int i = 0; i < 4; ++i)
#pragma unroll
    for (int j = 0; j < 4; ++j) acc[i][j] = z4;

  auto stage = [&](int buf) {
#pragma unroll
    for (int i = 0; i < 2; ++i) {
      GLOAD16(pA[i], &As[buf][(w + 4 * i) * 512]);
      pA[i] += 32;
      GLOAD16(pB[i], &Bs[buf][(w + 4 * i) * 512]);
      pB[i] += 32;
    }
  };

  const int rr = lane & 15, kb = lane >> 4;
  auto compute = [&](int buf) {
    bf16x8 a8[4], b8[4];
#pragma unroll
    for (int f = 0; f < 4; ++f) {
      const int Ra = wm * 64 + f * 16 + rr;
      a8[f] = *(const bf16x8*)&As[buf][Ra * 32 + (kb ^ ((Ra >> 1) & 3)) * 8];
      const int Rb = wn * 64 + f * 16 + rr;
      b8[f] = *(const bf16x8*)&Bs[buf][Rb * 32 + (kb ^ ((Rb >> 1) & 3)) * 8];
    }
#pragma unroll
    for (int fm = 0; fm < 4; ++fm)
#pragma unroll
      for (int fn = 0; fn < 4; ++fn)
        acc[fm][fn] = __builtin_amdgcn_mfma_f32_16x16x32_bf16(
            a8[fm], b8[fn], acc[fm][fn], 0, 0, 0);
  };

  stage(0);
  __syncthreads();
  int cur = 0;
#pragma unroll 1
  for (int kt = 0; kt < 64; ++kt) { // K = Fn = 2048
    if (kt + 1 < 64) stage(cur ^ 1);
    compute(cur);
    __syncthreads();
    cur ^= 1;
  }

  // epilogue: atomic scatter-add into out[b, tok, :]
  const int b = mt >> 3;
  const int m0 = mt * 128 + wm * 64;
  const int colBase = nt * 128 + wn * 64 + (lane & 15);
  const int rb = (lane >> 4) << 2;
#pragma unroll
  for (int fm = 0; fm < 4; ++fm) {
#pragma unroll
    for (int j = 0; j < 4; ++j) {
      const int m = m0 + fm * 16 + rb + j;
      const int c = m & (Cn - 1);
      const int t = tok[((size_t)b * En + e) * Cn + c];
      float* orow = out + ((size_t)b * Sn + t) * Dn + colBase;
#pragma unroll
      for (int fn = 0; fn < 4; ++fn)
        atomicAdd(orow + fn * 16, acc[fm][fn][j]);
    }
  }
}

extern "C" void kernel_launch(void* const* d_in, const int* in_sizes, int n_in,
                              void* d_out, int out_size, void* d_ws,
                              size_t ws_size, hipStream_t stream) {
  const float* x = (const float*)d_in[0];
  const float* ew = (const float*)d_in[1];
  const int* tok = (const int*)d_in[2];
  const float* w1 = (const float*)d_in[3];
  const float* w2 = (const float*)d_in[4];
  const float* w3 = (const float*)d_in[5];
  float* out = (float*)d_out;

  const size_t wE = (size_t)En * Dn * Fn;      // 16.78M elems per weight
  const size_t xgE = (size_t)En * Mn * Dn;     // 33.55M elems
  const size_t hbE = (size_t)(En / 2) * Mn * Fn; // 33.55M elems (half)
  __bf16* w1T = (__bf16*)d_ws;
  __bf16* w2T = w1T + wE;
  __bf16* w3T = w2T + wE;
  __bf16* Xg = w3T + wE;
  __bf16* Hbh = Xg + xgE;
  const size_t need = (3 * wE + xgE + hbE) * sizeof(__bf16); // ~235MB
  if (ws_size < need) return; // fail loudly (output stays poisoned)

  (void)hipMemsetAsync(d_out, 0, (size_t)Bn * Sn * Dn * sizeof(float), stream);

  tcast_kernel<<<dim3(Fn / 32, Dn / 32, En), 256, 0, stream>>>(w1, w1T, Dn, Fn);
  tcast_kernel<<<dim3(Fn / 32, Dn / 32, En), 256, 0, stream>>>(w2, w2T, Dn, Fn);
  tcast_kernel<<<dim3(Dn / 32, Fn / 32, En), 256, 0, stream>>>(w3, w3T, Fn, Dn);
  gather_cast_kernel<<<dim3(En * Mn / 4), 256, 0, stream>>>(x, tok, Xg);
  for (int h = 0; h < 2; ++h) {
    gemm12_kernel<<<dim3(512, En / 2), 256, 0, stream>>>(Xg, ew, w1T, w2T, Hbh,
                                                         h * (En / 2));
    gemm3_kernel<<<dim3(256, En / 2), 256, 0, stream>>>(Hbh, w3T, tok, out,
                                                        h * (En / 2));
  }
}

// Round 4
// 673.443 us; speedup vs baseline: 1.6038x; 1.3640x over previous
//
#include <hip/hip_runtime.h>

#define Bn 4
#define Sn 4096
#define Dn 1024
#define En 8
#define Cn 1024
#define Fn 2048
#define Mn (Bn * Cn) // 4096 rows per expert (all batches)

typedef __bf16 bf16x4 __attribute__((ext_vector_type(4)));
typedef __bf16 bf16x8 __attribute__((ext_vector_type(8)));
typedef float f32x4 __attribute__((ext_vector_type(4)));

// async global->LDS, 16B per lane, linear LDS dest (wave-uniform base + lane*16)
#define GLOAD16(gsrc, ldst)                                                    \
  __builtin_amdgcn_global_load_lds(                                            \
      (const __attribute__((address_space(1))) void*)(gsrc),                   \
      (__attribute__((address_space(3))) void*)(ldst), 16, 0, 0)

#define VMCNT(n) asm volatile("s_waitcnt vmcnt(" #n ")" ::: "memory")
#define SCHEDB() __builtin_amdgcn_sched_barrier(0)

// ---- transpose + cast: in[e][K][N] f32  ->  out[e][N][K] bf16 ----
__global__ __launch_bounds__(256) void tcast_kernel(
    const float* __restrict__ in, __bf16* __restrict__ out, int K, int N) {
  __shared__ float t[32][33];
  const int e = blockIdx.z;
  const float* src = in + (size_t)e * K * N;
  __bf16* dst = out + (size_t)e * K * N;
  const int n0 = blockIdx.x << 5, k0 = blockIdx.y << 5;
  const int tx = threadIdx.x & 31, ty = threadIdx.x >> 5;
#pragma unroll
  for (int i = 0; i < 4; ++i)
    t[ty + i * 8][tx] = src[(size_t)(k0 + ty + i * 8) * N + (n0 + tx)];
  __syncthreads();
#pragma unroll
  for (int i = 0; i < 4; ++i)
    dst[(size_t)(n0 + ty + i * 8) * K + (k0 + tx)] = (__bf16)t[tx][ty + i * 8];
}

// ---- gather + cast: Xg[e][m][d] = bf16(x[b(m)][tok[b,e,c(m)]][d]) ----
__global__ __launch_bounds__(256) void gather_cast_kernel(
    const float* __restrict__ x, const int* __restrict__ tok,
    __bf16* __restrict__ Xg) {
  const int gid = blockIdx.x * 4 + (threadIdx.x >> 6); // row in [0, En*Mn)
  const int lane = threadIdx.x & 63;
  const int e = gid >> 12, m = gid & 4095, b = m >> 10, c = m & 1023;
  const int t = tok[((size_t)b * En + e) * Cn + c];
  const float* src = x + ((size_t)b * Sn + t) * Dn;
  __bf16* dst = Xg + (size_t)gid * Dn;
#pragma unroll
  for (int i = 0; i < 4; ++i) {
    f32x4 v = *(const f32x4*)(src + i * 256 + lane * 4);
    bf16x4 o;
    o[0] = (__bf16)v[0];
    o[1] = (__bf16)v[1];
    o[2] = (__bf16)v[2];
    o[3] = (__bf16)v[3];
    *(bf16x4*)(dst + i * 256 + lane * 4) = o;
  }
}

// ==== fused dual GEMM (w1,w2) + SwiGLU(+ew) -> Hbh bf16 [4][Mn][Fn] ====
// 256 M-rows x 128 F-cols output per block; virtual B = [w1T panel; w2T panel]
// (256 rows). 8 waves 2Mx4N; waves wc<2 = gate, wc>=2 = value (same m,f).
// BK=32, 4-deep LDS pipeline, counted vmcnt(8), raw s_barrier.
__global__ __launch_bounds__(512, 2) void gemm12_kernel(
    const __bf16* __restrict__ Xg, const float* __restrict__ ew,
    const __bf16* __restrict__ w1T, const __bf16* __restrict__ w2T,
    __bf16* __restrict__ Hbh, int e0) {
  __shared__ __align__(16) char lds[131072];
  __bf16* As = (__bf16*)lds;            // [4 buf][256][32]
  __bf16* Bs = (__bf16*)(lds + 65536);  // [4 buf][256][32]
  float* xch = (float*)lds;             // epilogue exchange [4][128][64]

  const int tid = threadIdx.x;
  const int lane = tid & 63, wid = tid >> 6;
  const int wr = wid >> 2, wc = wid & 3;
  const int mt = blockIdx.x, ft = blockIdx.y, eLoc = blockIdx.z;
  const int e = e0 + eLoc;

  const int srow = tid >> 2;                     // staging row 0..127
  const int sof = ((tid & 3) ^ (srow & 3)) << 3; // pre-swizzled elem offset

  const __bf16* pA0 = Xg + ((size_t)e * Mn + mt * 256 + srow) * Dn + sof;
  const __bf16* pA1 = pA0 + (size_t)128 * Dn;
  const __bf16* pB0 = w1T + ((size_t)e * Fn + ft * 128 + srow) * Dn + sof;
  const __bf16* pB1 = w2T + ((size_t)e * Fn + ft * 128 + srow) * Dn + sof;

  f32x4 acc[8][4];
  const f32x4 z4 = {0.f, 0.f, 0.f, 0.f};
#pragma unroll
  for (int i = 0; i < 8; ++i)
#pragma unroll
    for (int j = 0; j < 4; ++j) acc[i][j] = z4;

  auto stage = [&](int kt) {
    const int buf = kt & 3;
    const int ko = kt << 5;
    GLOAD16(pA0 + ko, As + buf * 8192 + wid * 512);
    GLOAD16(pA1 + ko, As + buf * 8192 + 4096 + wid * 512);
    GLOAD16(pB0 + ko, Bs + buf * 8192 + wid * 512);
    GLOAD16(pB1 + ko, Bs + buf * 8192 + 4096 + wid * 512);
  };

  const int kb = lane >> 4, rl = lane & 15;
  auto compute = [&](int buf) {
    const __bf16* Ab = As + buf * 8192;
    const __bf16* Bb = Bs + buf * 8192;
    bf16x8 a8[8], b8[4];
#pragma unroll
    for (int fm = 0; fm < 8; ++fm) {
      const int r = wr * 128 + fm * 16 + rl;
      a8[fm] = *(const bf16x8*)(Ab + r * 32 + ((kb ^ (r & 3)) << 3));
    }
#pragma unroll
    for (int fn = 0; fn < 4; ++fn) {
      const int r = wc * 64 + fn * 16 + rl;
      b8[fn] = *(const bf16x8*)(Bb + r * 32 + ((kb ^ (r & 3)) << 3));
    }
    __builtin_amdgcn_s_setprio(1);
#pragma unroll
    for (int fm = 0; fm < 8; ++fm)
#pragma unroll
      for (int fn = 0; fn < 4; ++fn)
        acc[fm][fn] = __builtin_amdgcn_mfma_f32_16x16x32_bf16(
            a8[fm], b8[fn], acc[fm][fn], 0, 0, 0);
    __builtin_amdgcn_s_setprio(0);
  };

  const int KT = Dn / 32; // 32
  stage(0);
  stage(1);
  stage(2);
#pragma unroll 1
  for (int kt = 0; kt < KT; ++kt) {
    SCHEDB();
    if (kt < KT - 2)
      VMCNT(8);
    else if (kt == KT - 2)
      VMCNT(4);
    else
      VMCNT(0);
    __builtin_amdgcn_s_barrier();
    SCHEDB();
    if (kt + 3 < KT) stage(kt + 3);
    compute(kt & 3);
  }

  // ---- epilogue: value waves export acc via LDS; gate waves combine ----
  __syncthreads();
  const int rl0 = (lane >> 4) << 2, cl = lane & 15;
  if (wc >= 2) {
    float* reg = xch + (wr * 2 + (wc - 2)) * 8192;
#pragma unroll
    for (int fm = 0; fm < 8; ++fm)
#pragma unroll
      for (int fn = 0; fn < 4; ++fn)
#pragma unroll
        for (int j = 0; j < 4; ++j)
          reg[(fm * 16 + rl0 + j) * 64 + fn * 16 + cl] = acc[fm][fn][j];
  }
  __syncthreads();
  if (wc < 2) {
    const float* reg = xch + (wr * 2 + wc) * 8192;
    const int m0 = mt * 256 + wr * 128;
    const int b = m0 >> 10;
    const size_t ewBase = ((size_t)b * En + e) * Cn;
    __bf16* hOut =
        Hbh + ((size_t)eLoc * Mn + m0) * Fn + ft * 128 + wc * 64;
#pragma unroll
    for (int fm = 0; fm < 8; ++fm)
#pragma unroll
      for (int j = 0; j < 4; ++j) {
        const int rloc = fm * 16 + rl0 + j;
        const float wgt = ew[ewBase + ((m0 + rloc) & (Cn - 1))];
#pragma unroll
        for (int fn = 0; fn < 4; ++fn) {
          const float g = acc[fm][fn][j];
          const float v = reg[rloc * 64 + fn * 16 + cl];
          const float h = (g / (1.f + __expf(-g))) * v * wgt;
          hOut[(size_t)rloc * Fn + fn * 16 + cl] = (__bf16)h;
        }
      }
  }
}

// ==== GEMM3: Hbh x w3T -> atomic scatter-add (ew folded into Hbh) ====
// 256x256 tile, same pipeline.
__global__ __launch_bounds__(512, 2) void gemm3_kernel(
    const __bf16* __restrict__ Hbh, const __bf16* __restrict__ w3T,
    const int* __restrict__ tok, float* __restrict__ out, int e0) {
  __shared__ __align__(16) char lds[131072];
  __bf16* As = (__bf16*)lds;
  __bf16* Bs = (__bf16*)(lds + 65536);

  const int tid = threadIdx.x;
  const int lane = tid & 63, wid = tid >> 6;
  const int wr = wid >> 2, wc = wid & 3;
  const int mt = blockIdx.x, nt = blockIdx.y, eLoc = blockIdx.z;
  const int e = e0 + eLoc;

  const int srow = tid >> 2;
  const int sof = ((tid & 3) ^ (srow & 3)) << 3;

  const __bf16* pA0 = Hbh + ((size_t)eLoc * Mn + mt * 256 + srow) * Fn + sof;
  const __bf16* pA1 = pA0 + (size_t)128 * Fn;
  const __bf16* pB0 = w3T + ((size_t)e * Dn + nt * 256 + srow) * Fn + sof;
  const __bf16* pB1 = pB0 + (size_t)128 * Fn;

  f32x4 acc[8][4];
  const f32x4 z4 = {0.f, 0.f, 0.f, 0.f};
#pragma unroll
  for (int i = 0; i < 8; ++i)
#pragma unroll
    for (int j = 0; j < 4; ++j) acc[i][j] = z4;

  auto stage = [&](int kt) {
    const int buf = kt & 3;
    const int ko = kt << 5;
    GLOAD16(pA0 + ko, As + buf * 8192 + wid * 512);
    GLOAD16(pA1 + ko, As + buf * 8192 + 4096 + wid * 512);
    GLOAD16(pB0 + ko, Bs + buf * 8192 + wid * 512);
    GLOAD16(pB1 + ko, Bs + buf * 8192 + 4096 + wid * 512);
  };

  const int kb = lane >> 4, rl = lane & 15;
  auto compute = [&](int buf) {
    const __bf16* Ab = As + buf * 8192;
    const __bf16* Bb = Bs + buf * 8192;
    bf16x8 a8[8], b8[4];
#pragma unroll
    for (int fm = 0; fm < 8; ++fm) {
      const int r = wr * 128 + fm * 16 + rl;
      a8[fm] = *(const bf16x8*)(Ab + r * 32 + ((kb ^ (r & 3)) << 3));
    }
#pragma unroll
    for (int fn = 0; fn < 4; ++fn) {
      const int r = wc * 64 + fn * 16 + rl;
      b8[fn] = *(const bf16x8*)(Bb + r * 32 + ((kb ^ (r & 3)) << 3));
    }
    __builtin_amdgcn_s_setprio(1);
#pragma unroll
    for (int fm = 0; fm < 8; ++fm)
#pragma unroll
      for (int fn = 0; fn < 4; ++fn)
        acc[fm][fn] = __builtin_amdgcn_mfma_f32_16x16x32_bf16(
            a8[fm], b8[fn], acc[fm][fn], 0, 0, 0);
    __builtin_amdgcn_s_setprio(0);
  };

  const int KT = Fn / 32; // 64
  stage(0);
  stage(1);
  stage(2);
#pragma unroll 1
  for (int kt = 0; kt < KT; ++kt) {
    SCHEDB();
    if (kt < KT - 2)
      VMCNT(8);
    else if (kt == KT - 2)
      VMCNT(4);
    else
      VMCNT(0);
    __builtin_amdgcn_s_barrier();
    SCHEDB();
    if (kt + 3 < KT) stage(kt + 3);
    compute(kt & 3);
  }

  // ---- epilogue: weighted atomic scatter-add into out[b, tok, :] ----
  const int m0 = mt * 256 + wr * 128;
  const int b = m0 >> 10;
  const int rl0 = (lane >> 4) << 2, cl = lane & 15;
  const int colBase = nt * 256 + wc * 64 + cl;
#pragma unroll
  for (int fm = 0; fm < 8; ++fm) {
#pragma unroll
    for (int j = 0; j < 4; ++j) {
      const int m = m0 + fm * 16 + rl0 + j;
      const int c = m & (Cn - 1);
      const int t = tok[((size_t)b * En + e) * Cn + c];
      float* orow = out + ((size_t)b * Sn + t) * Dn + colBase;
#pragma unroll
      for (int fn = 0; fn < 4; ++fn)
        atomicAdd(orow + fn * 16, acc[fm][fn][j]);
    }
  }
}

extern "C" void kernel_launch(void* const* d_in, const int* in_sizes, int n_in,
                              void* d_out, int out_size, void* d_ws,
                              size_t ws_size, hipStream_t stream) {
  const float* x = (const float*)d_in[0];
  const float* ew = (const float*)d_in[1];
  const int* tok = (const int*)d_in[2];
  const float* w1 = (const float*)d_in[3];
  const float* w2 = (const float*)d_in[4];
  const float* w3 = (const float*)d_in[5];
  float* out = (float*)d_out;

  const size_t wE = (size_t)En * Dn * Fn;        // 16.78M elems per weight
  const size_t xgE = (size_t)En * Mn * Dn;       // 33.55M elems
  const size_t hbE = (size_t)(En / 2) * Mn * Fn; // 33.55M elems (half)
  __bf16* w1T = (__bf16*)d_ws;
  __bf16* w2T = w1T + wE;
  __bf16* w3T = w2T + wE;
  __bf16* Xg = w3T + wE;
  __bf16* Hbh = Xg + xgE;
  const size_t need = (3 * wE + xgE + hbE) * sizeof(__bf16); // ~235MB
  if (ws_size < need) return; // fail loudly (output stays poisoned)

  (void)hipMemsetAsync(d_out, 0, (size_t)Bn * Sn * Dn * sizeof(float), stream);

  tcast_kernel<<<dim3(Fn / 32, Dn / 32, En), 256, 0, stream>>>(w1, w1T, Dn, Fn);
  tcast_kernel<<<dim3(Fn / 32, Dn / 32, En), 256, 0, stream>>>(w2, w2T, Dn, Fn);
  tcast_kernel<<<dim3(Dn / 32, Fn / 32, En), 256, 0, stream>>>(w3, w3T, Fn, Dn);
  gather_cast_kernel<<<dim3(En * Mn / 4), 256, 0, stream>>>(x, tok, Xg);
  for (int h = 0; h < 2; ++h) {
    // grid: mt fastest (x) -> default XCD round-robin keeps A-panels L2-local
    gemm12_kernel<<<dim3(16, 16, En / 2), 512, 0, stream>>>(Xg, ew, w1T, w2T,
                                                            Hbh, h * (En / 2));
    gemm3_kernel<<<dim3(16, 4, En / 2), 512, 0, stream>>>(Hbh, w3T, tok, out,
                                                          h * (En / 2));
  }
}

// Round 5
// 662.901 us; speedup vs baseline: 1.6293x; 1.0159x over previous
//
#include <hip/hip_runtime.h>

#define Bn 4
#define Sn 4096
#define Dn 1024
#define En 8
#define Cn 1024
#define Fn 2048
#define Mn (Bn * Cn) // 4096 rows per expert (all batches)

typedef __bf16 bf16x4 __attribute__((ext_vector_type(4)));
typedef __bf16 bf16x8 __attribute__((ext_vector_type(8)));
typedef float f32x4 __attribute__((ext_vector_type(4)));

// async global->LDS, 16B per lane, linear LDS dest (wave-uniform base + lane*16)
#define GLOAD16(gsrc, ldst)                                                    \
  __builtin_amdgcn_global_load_lds(                                            \
      (const __attribute__((address_space(1))) void*)(gsrc),                   \
      (__attribute__((address_space(3))) void*)(ldst), 16, 0, 0)

#define VMCNT(n) asm volatile("s_waitcnt vmcnt(" #n ")" ::: "memory")
#define SCHEDB() __builtin_amdgcn_sched_barrier(0)

// ---- transpose + cast: in[e][K][N] f32  ->  out[e][N][K] bf16 ----
__global__ __launch_bounds__(256) void tcast_kernel(
    const float* __restrict__ in, __bf16* __restrict__ out, int K, int N) {
  __shared__ float t[32][33];
  const int e = blockIdx.z;
  const float* src = in + (size_t)e * K * N;
  __bf16* dst = out + (size_t)e * K * N;
  const int n0 = blockIdx.x << 5, k0 = blockIdx.y << 5;
  const int tx = threadIdx.x & 31, ty = threadIdx.x >> 5;
#pragma unroll
  for (int i = 0; i < 4; ++i)
    t[ty + i * 8][tx] = src[(size_t)(k0 + ty + i * 8) * N + (n0 + tx)];
  __syncthreads();
#pragma unroll
  for (int i = 0; i < 4; ++i)
    dst[(size_t)(n0 + ty + i * 8) * K + (k0 + tx)] = (__bf16)t[tx][ty + i * 8];
}

// ---- gather + cast: Xg[e][m][d] = bf16(x[b(m)][tok[b,e,c(m)]][d]) ----
__global__ __launch_bounds__(256) void gather_cast_kernel(
    const float* __restrict__ x, const int* __restrict__ tok,
    __bf16* __restrict__ Xg) {
  const int gid = blockIdx.x * 4 + (threadIdx.x >> 6); // row in [0, En*Mn)
  const int lane = threadIdx.x & 63;
  const int e = gid >> 12, m = gid & 4095, b = m >> 10, c = m & 1023;
  const int t = tok[((size_t)b * En + e) * Cn + c];
  const float* src = x + ((size_t)b * Sn + t) * Dn;
  __bf16* dst = Xg + (size_t)gid * Dn;
#pragma unroll
  for (int i = 0; i < 4; ++i) {
    f32x4 v = *(const f32x4*)(src + i * 256 + lane * 4);
    bf16x4 o;
    o[0] = (__bf16)v[0];
    o[1] = (__bf16)v[1];
    o[2] = (__bf16)v[2];
    o[3] = (__bf16)v[3];
    *(bf16x4*)(dst + i * 256 + lane * 4) = o;
  }
}

// ==== fused dual GEMM (w1,w2) + SwiGLU(+ew) -> Hbh bf16 [4][Mn][Fn] ====
// 256 M-rows x 128 F-cols output per block; virtual B = [w1T panel; w2T panel]
// (256 rows). 8 waves 2Mx4N; waves wc<2 = gate, wc>=2 = value (same m,f).
// BK=32, 4-deep LDS pipeline, counted vmcnt(8), raw s_barrier.
__global__ __launch_bounds__(512, 2) void gemm12_kernel(
    const __bf16* __restrict__ Xg, const float* __restrict__ ew,
    const __bf16* __restrict__ w1T, const __bf16* __restrict__ w2T,
    __bf16* __restrict__ Hbh, int e0) {
  __shared__ __align__(16) char lds[131072];
  __bf16* As = (__bf16*)lds;            // [4 buf][256][32]
  __bf16* Bs = (__bf16*)(lds + 65536);  // [4 buf][256][32]
  float* xch = (float*)lds;             // epilogue exchange [4][128][64]

  const int tid = threadIdx.x;
  const int lane = tid & 63, wid = tid >> 6;
  const int wr = wid >> 2, wc = wid & 3;
  const int mt = blockIdx.x, ft = blockIdx.y, eLoc = blockIdx.z;
  const int e = e0 + eLoc;

  const int srow = tid >> 2;                            // staging row 0..127
  const int sof = ((tid & 3) ^ ((tid >> 3) & 3)) << 3;  // pre-swz (2-way free)

  const __bf16* pA0 = Xg + ((size_t)e * Mn + mt * 256 + srow) * Dn + sof;
  const __bf16* pA1 = pA0 + (size_t)128 * Dn;
  const __bf16* pB0 = w1T + ((size_t)e * Fn + ft * 128 + srow) * Dn + sof;
  const __bf16* pB1 = w2T + ((size_t)e * Fn + ft * 128 + srow) * Dn + sof;

  f32x4 acc[8][4];
  const f32x4 z4 = {0.f, 0.f, 0.f, 0.f};
#pragma unroll
  for (int i = 0; i < 8; ++i)
#pragma unroll
    for (int j = 0; j < 4; ++j) acc[i][j] = z4;

  auto stage = [&](int kt) {
    const int buf = kt & 3;
    const int ko = kt << 5;
    GLOAD16(pA0 + ko, As + buf * 8192 + wid * 512);
    GLOAD16(pA1 + ko, As + buf * 8192 + 4096 + wid * 512);
    GLOAD16(pB0 + ko, Bs + buf * 8192 + wid * 512);
    GLOAD16(pB1 + ko, Bs + buf * 8192 + 4096 + wid * 512);
  };

  const int kb = lane >> 4, rl = lane & 15;
  auto compute = [&](int buf) {
    const __bf16* Ab = As + buf * 8192;
    const __bf16* Bb = Bs + buf * 8192;
    bf16x8 a8[8], b8[4];
#pragma unroll
    for (int fm = 0; fm < 8; ++fm) {
      const int r = wr * 128 + fm * 16 + rl;
      a8[fm] = *(const bf16x8*)(Ab + r * 32 + ((kb ^ ((r >> 1) & 3)) << 3));
    }
#pragma unroll
    for (int fn = 0; fn < 4; ++fn) {
      const int r = wc * 64 + fn * 16 + rl;
      b8[fn] = *(const bf16x8*)(Bb + r * 32 + ((kb ^ ((r >> 1) & 3)) << 3));
    }
    __builtin_amdgcn_s_setprio(1);
#pragma unroll
    for (int fm = 0; fm < 8; ++fm)
#pragma unroll
      for (int fn = 0; fn < 4; ++fn)
        acc[fm][fn] = __builtin_amdgcn_mfma_f32_16x16x32_bf16(
            a8[fm], b8[fn], acc[fm][fn], 0, 0, 0);
    __builtin_amdgcn_s_setprio(0);
  };

  const int KT = Dn / 32; // 32
  stage(0);
  stage(1);
  stage(2);
#pragma unroll 1
  for (int kt = 0; kt < KT; ++kt) {
    SCHEDB();
    if (kt < KT - 2)
      VMCNT(8);
    else if (kt == KT - 2)
      VMCNT(4);
    else
      VMCNT(0);
    __builtin_amdgcn_s_barrier();
    SCHEDB();
    if (kt + 3 < KT) stage(kt + 3);
    compute(kt & 3);
  }

  // ---- epilogue: value waves export acc via LDS; gate waves combine ----
  // xch layout: row*64 + (fn ^ ((row>>2)&3))*16 + col  -> 2-way banks (free)
  __syncthreads();
  const int rl0 = (lane >> 4) << 2, cl = lane & 15;
  if (wc >= 2) {
    float* reg = xch + (wr * 2 + (wc - 2)) * 8192;
#pragma unroll
    for (int fm = 0; fm < 8; ++fm)
#pragma unroll
      for (int fn = 0; fn < 4; ++fn)
#pragma unroll
        for (int j = 0; j < 4; ++j) {
          const int row = fm * 16 + rl0 + j;
          reg[row * 64 + ((fn ^ ((row >> 2) & 3)) << 4) + cl] = acc[fm][fn][j];
        }
  }
  __syncthreads();
  if (wc < 2) {
    const float* reg = xch + (wr * 2 + wc) * 8192;
    const int m0 = mt * 256 + wr * 128;
    const int b = m0 >> 10;
    const size_t ewBase = ((size_t)b * En + e) * Cn;
    __bf16* hOut =
        Hbh + ((size_t)eLoc * Mn + m0) * Fn + ft * 128 + wc * 64;
#pragma unroll
    for (int fm = 0; fm < 8; ++fm)
#pragma unroll
      for (int j = 0; j < 4; ++j) {
        const int rloc = fm * 16 + rl0 + j;
        const float wgt = ew[ewBase + ((m0 + rloc) & (Cn - 1))];
#pragma unroll
        for (int fn = 0; fn < 4; ++fn) {
          const float g = acc[fm][fn][j];
          const float v = reg[rloc * 64 + ((fn ^ ((rloc >> 2) & 3)) << 4) + cl];
          const float h = (g / (1.f + __expf(-g))) * v * wgt;
          hOut[(size_t)rloc * Fn + fn * 16 + cl] = (__bf16)h;
        }
      }
  }
}

// ==== GEMM3: Hbh x w3T -> atomic scatter-add (ew folded into Hbh) ====
// 256x256 tile, same pipeline.
__global__ __launch_bounds__(512, 2) void gemm3_kernel(
    const __bf16* __restrict__ Hbh, const __bf16* __restrict__ w3T,
    const int* __restrict__ tok, float* __restrict__ out, int e0) {
  __shared__ __align__(16) char lds[131072];
  __bf16* As = (__bf16*)lds;
  __bf16* Bs = (__bf16*)(lds + 65536);

  const int tid = threadIdx.x;
  const int lane = tid & 63, wid = tid >> 6;
  const int wr = wid >> 2, wc = wid & 3;
  const int mt = blockIdx.x, nt = blockIdx.y, eLoc = blockIdx.z;
  const int e = e0 + eLoc;

  const int srow = tid >> 2;
  const int sof = ((tid & 3) ^ ((tid >> 3) & 3)) << 3;

  const __bf16* pA0 = Hbh + ((size_t)eLoc * Mn + mt * 256 + srow) * Fn + sof;
  const __bf16* pA1 = pA0 + (size_t)128 * Fn;
  const __bf16* pB0 = w3T + ((size_t)e * Dn + nt * 256 + srow) * Fn + sof;
  const __bf16* pB1 = pB0 + (size_t)128 * Fn;

  f32x4 acc[8][4];
  const f32x4 z4 = {0.f, 0.f, 0.f, 0.f};
#pragma unroll
  for (int i = 0; i < 8; ++i)
#pragma unroll
    for (int j = 0; j < 4; ++j) acc[i][j] = z4;

  auto stage = [&](int kt) {
    const int buf = kt & 3;
    const int ko = kt << 5;
    GLOAD16(pA0 + ko, As + buf * 8192 + wid * 512);
    GLOAD16(pA1 + ko, As + buf * 8192 + 4096 + wid * 512);
    GLOAD16(pB0 + ko, Bs + buf * 8192 + wid * 512);
    GLOAD16(pB1 + ko, Bs + buf * 8192 + 4096 + wid * 512);
  };

  const int kb = lane >> 4, rl = lane & 15;
  auto compute = [&](int buf) {
    const __bf16* Ab = As + buf * 8192;
    const __bf16* Bb = Bs + buf * 8192;
    bf16x8 a8[8], b8[4];
#pragma unroll
    for (int fm = 0; fm < 8; ++fm) {
      const int r = wr * 128 + fm * 16 + rl;
      a8[fm] = *(const bf16x8*)(Ab + r * 32 + ((kb ^ ((r >> 1) & 3)) << 3));
    }
#pragma unroll
    for (int fn = 0; fn < 4; ++fn) {
      const int r = wc * 64 + fn * 16 + rl;
      b8[fn] = *(const bf16x8*)(Bb + r * 32 + ((kb ^ ((r >> 1) & 3)) << 3));
    }
    __builtin_amdgcn_s_setprio(1);
#pragma unroll
    for (int fm = 0; fm < 8; ++fm)
#pragma unroll
      for (int fn = 0; fn < 4; ++fn)
        acc[fm][fn] = __builtin_amdgcn_mfma_f32_16x16x32_bf16(
            a8[fm], b8[fn], acc[fm][fn], 0, 0, 0);
    __builtin_amdgcn_s_setprio(0);
  };

  const int KT = Fn / 32; // 64
  stage(0);
  stage(1);
  stage(2);
#pragma unroll 1
  for (int kt = 0; kt < KT; ++kt) {
    SCHEDB();
    if (kt < KT - 2)
      VMCNT(8);
    else if (kt == KT - 2)
      VMCNT(4);
    else
      VMCNT(0);
    __builtin_amdgcn_s_barrier();
    SCHEDB();
    if (kt + 3 < KT) stage(kt + 3);
    compute(kt & 3);
  }

  // ---- epilogue: weighted atomic scatter-add into out[b, tok, :] ----
  const int m0 = mt * 256 + wr * 128;
  const int b = m0 >> 10;
  const int rl0 = (lane >> 4) << 2, cl = lane & 15;
  const int colBase = nt * 256 + wc * 64 + cl;
#pragma unroll
  for (int fm = 0; fm < 8; ++fm) {
#pragma unroll
    for (int j = 0; j < 4; ++j) {
      const int m = m0 + fm * 16 + rl0 + j;
      const int c = m & (Cn - 1);
      const int t = tok[((size_t)b * En + e) * Cn + c];
      float* orow = out + ((size_t)b * Sn + t) * Dn + colBase;
#pragma unroll
      for (int fn = 0; fn < 4; ++fn)
        atomicAdd(orow + fn * 16, acc[fm][fn][j]);
    }
  }
}

extern "C" void kernel_launch(void* const* d_in, const int* in_sizes, int n_in,
                              void* d_out, int out_size, void* d_ws,
                              size_t ws_size, hipStream_t stream) {
  const float* x = (const float*)d_in[0];
  const float* ew = (const float*)d_in[1];
  const int* tok = (const int*)d_in[2];
  const float* w1 = (const float*)d_in[3];
  const float* w2 = (const float*)d_in[4];
  const float* w3 = (const float*)d_in[5];
  float* out = (float*)d_out;

  const size_t wE = (size_t)En * Dn * Fn;        // 16.78M elems per weight
  const size_t xgE = (size_t)En * Mn * Dn;       // 33.55M elems
  const size_t hbE = (size_t)(En / 2) * Mn * Fn; // 33.55M elems (half)
  __bf16* w1T = (__bf16*)d_ws;
  __bf16* w2T = w1T + wE;
  __bf16* w3T = w2T + wE;
  __bf16* Xg = w3T + wE;
  __bf16* Hbh = Xg + xgE;
  const size_t need = (3 * wE + xgE + hbE) * sizeof(__bf16); // ~235MB
  if (ws_size < need) return; // fail loudly (output stays poisoned)

  (void)hipMemsetAsync(d_out, 0, (size_t)Bn * Sn * Dn * sizeof(float), stream);

  tcast_kernel<<<dim3(Fn / 32, Dn / 32, En), 256, 0, stream>>>(w1, w1T, Dn, Fn);
  tcast_kernel<<<dim3(Fn / 32, Dn / 32, En), 256, 0, stream>>>(w2, w2T, Dn, Fn);
  tcast_kernel<<<dim3(Dn / 32, Fn / 32, En), 256, 0, stream>>>(w3, w3T, Fn, Dn);
  gather_cast_kernel<<<dim3(En * Mn / 4), 256, 0, stream>>>(x, tok, Xg);
  for (int h = 0; h < 2; ++h) {
    // grid: mt fastest (x) -> default XCD round-robin keeps A-panels L2-local
    gemm12_kernel<<<dim3(16, 16, En / 2), 512, 0, stream>>>(Xg, ew, w1T, w2T,
                                                            Hbh, h * (En / 2));
    gemm3_kernel<<<dim3(16, 4, En / 2), 512, 0, stream>>>(Hbh, w3T, tok, out,
                                                          h * (En / 2));
  }
}

// Round 6
// 660.687 us; speedup vs baseline: 1.6348x; 1.0034x over previous
//
#include <hip/hip_runtime.h>

#define Bn 4
#define Sn 4096
#define Dn 1024
#define En 8
#define Cn 1024
#define Fn 2048
#define Mn (Bn * Cn) // 4096 rows per expert (all batches)

typedef __bf16 bf16x4 __attribute__((ext_vector_type(4)));
typedef __bf16 bf16x8 __attribute__((ext_vector_type(8)));
typedef float f32x4 __attribute__((ext_vector_type(4)));

// async global->LDS, 16B per lane, linear LDS dest (wave-uniform base + lane*16)
#define GLOAD16(gsrc, ldst)                                                    \
  __builtin_amdgcn_global_load_lds(                                            \
      (const __attribute__((address_space(1))) void*)(gsrc),                   \
      (__attribute__((address_space(3))) void*)(ldst), 16, 0, 0)

#define VMCNT(n) asm volatile("s_waitcnt vmcnt(" #n ")" ::: "memory")
#define LGKM0() asm volatile("s_waitcnt lgkmcnt(0)" ::: "memory")
#define SCHEDB() __builtin_amdgcn_sched_barrier(0)
#define SBAR() __builtin_amdgcn_s_barrier()
#define PRIO(p) __builtin_amdgcn_s_setprio(p)

// ---- transpose + cast: in[e][K][N] f32  ->  out[e][N][K] bf16 ----
__global__ __launch_bounds__(256) void tcast_kernel(
    const float* __restrict__ in, __bf16* __restrict__ out, int K, int N) {
  __shared__ float t[32][33];
  const int e = blockIdx.z;
  const float* src = in + (size_t)e * K * N;
  __bf16* dst = out + (size_t)e * K * N;
  const int n0 = blockIdx.x << 5, k0 = blockIdx.y << 5;
  const int tx = threadIdx.x & 31, ty = threadIdx.x >> 5;
#pragma unroll
  for (int i = 0; i < 4; ++i)
    t[ty + i * 8][tx] = src[(size_t)(k0 + ty + i * 8) * N + (n0 + tx)];
  __syncthreads();
#pragma unroll
  for (int i = 0; i < 4; ++i)
    dst[(size_t)(n0 + ty + i * 8) * K + (k0 + tx)] = (__bf16)t[tx][ty + i * 8];
}

// ---- gather + cast: Xg[e][m][d] = bf16(x[b(m)][tok[b,e,c(m)]][d]) ----
__global__ __launch_bounds__(256) void gather_cast_kernel(
    const float* __restrict__ x, const int* __restrict__ tok,
    __bf16* __restrict__ Xg) {
  const int gid = blockIdx.x * 4 + (threadIdx.x >> 6); // row in [0, En*Mn)
  const int lane = threadIdx.x & 63;
  const int e = gid >> 12, m = gid & 4095, b = m >> 10, c = m & 1023;
  const int t = tok[((size_t)b * En + e) * Cn + c];
  const float* src = x + ((size_t)b * Sn + t) * Dn;
  __bf16* dst = Xg + (size_t)gid * Dn;
#pragma unroll
  for (int i = 0; i < 4; ++i) {
    f32x4 v = *(const f32x4*)(src + i * 256 + lane * 4);
    bf16x4 o;
    o[0] = (__bf16)v[0];
    o[1] = (__bf16)v[1];
    o[2] = (__bf16)v[2];
    o[3] = (__bf16)v[3];
    *(bf16x4*)(dst + i * 256 + lane * 4) = o;
  }
}

// ======================= 8-phase GEMM core notes =======================
// BK=64 split into 2 k-halves (ks). LDS per matrix: 4 slots [par][ks] of
// 16KB (256 rows x 32 k bf16, rows-major 64B/row). Phases per K-tile c
// (par=c&1): (ks0,fh0) (ks0,fh1) (ks1,fh0) (ks1,fh1); each phase: ds_read
// {8 or 4} b128, stage 1 half-tile (2 gloads), barrier, lgkm0, 16 MFMA,
// barrier. Staging rule: ph0 -> A-kh1 of c+1 (slot par^1); ph1 -> B-kh0 of
// c+2 (slot par); ph2 -> A-kh0 of c+2; ph3 -> B-kh1 of c+2; vmcnt(6) at
// ph3 end covers K-tile c+1 fully (3 half-tiles = 6 loads outstanding).
// Slot is always freed (last reader phase's end-barrier passed) before its
// re-stage is issued. Swizzle: global source k-block pre-XOR ((t>>3)&3);
// read side blk = kb ^ ((row>>1)&3) -> 2-way banks (free).

// ==== fused dual GEMM (w1,w2) + SwiGLU(+ew) -> Hbh bf16 [4][Mn][Fn] ====
__global__ __launch_bounds__(512, 2) void gemm12_kernel(
    const __bf16* __restrict__ Xg, const float* __restrict__ ew,
    const __bf16* __restrict__ w1T, const __bf16* __restrict__ w2T,
    __bf16* __restrict__ Hbh, int e0) {
  __shared__ __align__(16) char lds[131072];
  float* xch = (float*)lds; // epilogue exchange (reused after drain)

  const int tid = threadIdx.x;
  const int lane = tid & 63, wid = tid >> 6;
  const int wr = wid >> 2, wc = wid & 3;
  const int mt = blockIdx.x, ft = blockIdx.y, eLoc = blockIdx.z;
  const int e = e0 + eLoc;

  // staging: thread t -> row (t>>2), 16B k-block (t&3), source pre-swizzled
  const int srow = tid >> 2;
  const int sof = ((tid & 3) ^ ((tid >> 3) & 3)) << 3;
  const __bf16* pA0 = Xg + ((size_t)e * Mn + mt * 256 + srow) * Dn + sof;
  const __bf16* pA1 = pA0 + (size_t)128 * Dn;
  const __bf16* pB0 = w1T + ((size_t)e * Fn + ft * 128 + srow) * Dn + sof;
  const __bf16* pB1 = w2T + ((size_t)e * Fn + ft * 128 + srow) * Dn + sof;

  char* sA = lds + tid * 16;
  char* sB = lds + 65536 + tid * 16;

  auto stageA = [&](int src, int par, int kh) {
    const int ko = (src << 6) + (kh << 5);
    char* d = sA + ((par * 2 + kh) << 14);
    GLOAD16(pA0 + ko, d);
    GLOAD16(pA1 + ko, d + 8192);
  };
  auto stageB = [&](int src, int par, int kh) {
    const int ko = (src << 6) + (kh << 5);
    char* d = sB + ((par * 2 + kh) << 14);
    GLOAD16(pB0 + ko, d);
    GLOAD16(pB1 + ko, d + 8192);
  };

  // fragment reads
  const int rl = lane & 15, kb = lane >> 4;
  const int swz = (kb ^ ((rl >> 1) & 3)) << 4; // byte offset of 16B block
  const char* aLane = lds + (wr * 128 + rl) * 64 + swz;
  const char* bLane = lds + 65536 + (wc * 64 + rl) * 64 + swz;

  f32x4 acc[8][4];
  const f32x4 z4 = {0.f, 0.f, 0.f, 0.f};
#pragma unroll
  for (int i = 0; i < 8; ++i)
#pragma unroll
    for (int j = 0; j < 4; ++j) acc[i][j] = z4;

  bf16x8 a4[4], b4[4];
  auto readA = [&](int par, int ks, int fh) {
    const char* p = aLane + ((par * 2 + ks) << 14) + (fh << 12);
#pragma unroll
    for (int i = 0; i < 4; ++i) a4[i] = *(const bf16x8*)(p + (i << 10));
  };
  auto readB = [&](int par, int ks) {
    const char* p = bLane + ((par * 2 + ks) << 14);
#pragma unroll
    for (int i = 0; i < 4; ++i) b4[i] = *(const bf16x8*)(p + (i << 10));
  };
  auto mfma16 = [&](int fh) {
    PRIO(1);
#pragma unroll
    for (int i = 0; i < 4; ++i)
#pragma unroll
      for (int j = 0; j < 4; ++j)
        acc[fh * 4 + i][j] = __builtin_amdgcn_mfma_f32_16x16x32_bf16(
            a4[i], b4[j], acc[fh * 4 + i][j], 0, 0, 0);
    PRIO(0);
  };

  // prologue: 7 half-tiles in steady-state order
  stageB(0, 0, 0); stageA(0, 0, 0); stageB(0, 0, 1); stageA(0, 0, 1);
  stageB(1, 1, 0); stageA(1, 1, 0); stageB(1, 1, 1);
  VMCNT(6);
  SBAR();
  SCHEDB();

  const int KT = Dn >> 6; // 16
#pragma unroll 1
  for (int c = 0; c < KT; ++c) {
    const int par = c & 1;
    const int n1 = (c + 1 < KT) ? c + 1 : KT - 1;
    const int n2 = (c + 2 < KT) ? c + 2 : KT - 1;
    // phase 0: (ks0, fh0)
    readA(par, 0, 0);
    readB(par, 0);
    stageA(n1, par ^ 1, 1);
    SBAR(); LGKM0(); SCHEDB();
    mfma16(0);
    SBAR(); SCHEDB();
    // phase 1: (ks0, fh1) — reuse b4
    readA(par, 0, 1);
    stageB(n2, par, 0);
    SBAR(); LGKM0(); SCHEDB();
    mfma16(1);
    SBAR(); SCHEDB();
    // phase 2: (ks1, fh0)
    readA(par, 1, 0);
    readB(par, 1);
    stageA(n2, par, 0);
    SBAR(); LGKM0(); SCHEDB();
    mfma16(0);
    SBAR(); SCHEDB();
    // phase 3: (ks1, fh1)
    readA(par, 1, 1);
    stageB(n2, par, 1);
    SBAR(); LGKM0(); SCHEDB();
    mfma16(1);
    VMCNT(6);
    SBAR(); SCHEDB();
  }
  VMCNT(0);
  __syncthreads();

  // ---- epilogue: value waves export acc via LDS; gate waves combine ----
  // xch layout: row*64 + (fn ^ ((row>>2)&3))*16 + col -> 2-way banks (free)
  const int rl0 = (lane >> 4) << 2, cl = lane & 15;
  if (wc >= 2) {
    float* reg = xch + (wr * 2 + (wc - 2)) * 8192;
#pragma unroll
    for (int fm = 0; fm < 8; ++fm)
#pragma unroll
      for (int fn = 0; fn < 4; ++fn)
#pragma unroll
        for (int j = 0; j < 4; ++j) {
          const int row = fm * 16 + rl0 + j;
          reg[row * 64 + ((fn ^ ((row >> 2) & 3)) << 4) + cl] = acc[fm][fn][j];
        }
  }
  __syncthreads();
  if (wc < 2) {
    const float* reg = xch + (wr * 2 + wc) * 8192;
    const int m0 = mt * 256 + wr * 128;
    const int b = m0 >> 10;
    const size_t ewBase = ((size_t)b * En + e) * Cn;
    __bf16* hOut = Hbh + ((size_t)eLoc * Mn + m0) * Fn + ft * 128 + wc * 64;
#pragma unroll
    for (int fm = 0; fm < 8; ++fm)
#pragma unroll
      for (int j = 0; j < 4; ++j) {
        const int rloc = fm * 16 + rl0 + j;
        const float wgt = ew[ewBase + ((m0 + rloc) & (Cn - 1))];
#pragma unroll
        for (int fn = 0; fn < 4; ++fn) {
          const float g = acc[fm][fn][j];
          const float v = reg[rloc * 64 + ((fn ^ ((rloc >> 2) & 3)) << 4) + cl];
          const float h = (g / (1.f + __expf(-g))) * v * wgt;
          hOut[(size_t)rloc * Fn + fn * 16 + cl] = (__bf16)h;
        }
      }
  }
}

// ==== GEMM3: Hbh x w3T (256x256 tile) -> atomic scatter-add ====
__global__ __launch_bounds__(512, 2) void gemm3_kernel(
    const __bf16* __restrict__ Hbh, const __bf16* __restrict__ w3T,
    const int* __restrict__ tok, float* __restrict__ out, int e0) {
  __shared__ __align__(16) char lds[131072];

  const int tid = threadIdx.x;
  const int lane = tid & 63, wid = tid >> 6;
  const int wr = wid >> 2, wc = wid & 3;
  const int mt = blockIdx.x, nt = blockIdx.y, eLoc = blockIdx.z;
  const int e = e0 + eLoc;

  const int srow = tid >> 2;
  const int sof = ((tid & 3) ^ ((tid >> 3) & 3)) << 3;
  const __bf16* pA0 = Hbh + ((size_t)eLoc * Mn + mt * 256 + srow) * Fn + sof;
  const __bf16* pA1 = pA0 + (size_t)128 * Fn;
  const __bf16* pB0 = w3T + ((size_t)e * Dn + nt * 256 + srow) * Fn + sof;
  const __bf16* pB1 = pB0 + (size_t)128 * Fn;

  char* sA = lds + tid * 16;
  char* sB = lds + 65536 + tid * 16;

  auto stageA = [&](int src, int par, int kh) {
    const int ko = (src << 6) + (kh << 5);
    char* d = sA + ((par * 2 + kh) << 14);
    GLOAD16(pA0 + ko, d);
    GLOAD16(pA1 + ko, d + 8192);
  };
  auto stageB = [&](int src, int par, int kh) {
    const int ko = (src << 6) + (kh << 5);
    char* d = sB + ((par * 2 + kh) << 14);
    GLOAD16(pB0 + ko, d);
    GLOAD16(pB1 + ko, d + 8192);
  };

  const int rl = lane & 15, kb = lane >> 4;
  const int swz = (kb ^ ((rl >> 1) & 3)) << 4;
  const char* aLane = lds + (wr * 128 + rl) * 64 + swz;
  const char* bLane = lds + 65536 + (wc * 64 + rl) * 64 + swz;

  f32x4 acc[8][4];
  const f32x4 z4 = {0.f, 0.f, 0.f, 0.f};
#pragma unroll
  for (int i = 0; i < 8; ++i)
#pragma unroll
    for (int j = 0; j < 4; ++j) acc[i][j] = z4;

  bf16x8 a4[4], b4[4];
  auto readA = [&](int par, int ks, int fh) {
    const char* p = aLane + ((par * 2 + ks) << 14) + (fh << 12);
#pragma unroll
    for (int i = 0; i < 4; ++i) a4[i] = *(const bf16x8*)(p + (i << 10));
  };
  auto readB = [&](int par, int ks) {
    const char* p = bLane + ((par * 2 + ks) << 14);
#pragma unroll
    for (int i = 0; i < 4; ++i) b4[i] = *(const bf16x8*)(p + (i << 10));
  };
  auto mfma16 = [&](int fh) {
    PRIO(1);
#pragma unroll
    for (int i = 0; i < 4; ++i)
#pragma unroll
      for (int j = 0; j < 4; ++j)
        acc[fh * 4 + i][j] = __builtin_amdgcn_mfma_f32_16x16x32_bf16(
            a4[i], b4[j], acc[fh * 4 + i][j], 0, 0, 0);
    PRIO(0);
  };

  stageB(0, 0, 0); stageA(0, 0, 0); stageB(0, 0, 1); stageA(0, 0, 1);
  stageB(1, 1, 0); stageA(1, 1, 0); stageB(1, 1, 1);
  VMCNT(6);
  SBAR();
  SCHEDB();

  const int KT = Fn >> 6; // 32
#pragma unroll 1
  for (int c = 0; c < KT; ++c) {
    const int par = c & 1;
    const int n1 = (c + 1 < KT) ? c + 1 : KT - 1;
    const int n2 = (c + 2 < KT) ? c + 2 : KT - 1;
    readA(par, 0, 0);
    readB(par, 0);
    stageA(n1, par ^ 1, 1);
    SBAR(); LGKM0(); SCHEDB();
    mfma16(0);
    SBAR(); SCHEDB();
    readA(par, 0, 1);
    stageB(n2, par, 0);
    SBAR(); LGKM0(); SCHEDB();
    mfma16(1);
    SBAR(); SCHEDB();
    readA(par, 1, 0);
    readB(par, 1);
    stageA(n2, par, 0);
    SBAR(); LGKM0(); SCHEDB();
    mfma16(0);
    SBAR(); SCHEDB();
    readA(par, 1, 1);
    stageB(n2, par, 1);
    SBAR(); LGKM0(); SCHEDB();
    mfma16(1);
    VMCNT(6);
    SBAR(); SCHEDB();
  }
  VMCNT(0);

  // ---- epilogue: weighted atomic scatter-add into out[b, tok, :] ----
  const int m0 = mt * 256 + wr * 128;
  const int b = m0 >> 10;
  const int rl0 = (lane >> 4) << 2, cl = lane & 15;
  const int colBase = nt * 256 + wc * 64 + cl;
#pragma unroll
  for (int fm = 0; fm < 8; ++fm) {
#pragma unroll
    for (int j = 0; j < 4; ++j) {
      const int m = m0 + fm * 16 + rl0 + j;
      const int c2 = m & (Cn - 1);
      const int t = tok[((size_t)b * En + e) * Cn + c2];
      float* orow = out + ((size_t)b * Sn + t) * Dn + colBase;
#pragma unroll
      for (int fn = 0; fn < 4; ++fn)
        atomicAdd(orow + fn * 16, acc[fm][fn][j]);
    }
  }
}

extern "C" void kernel_launch(void* const* d_in, const int* in_sizes, int n_in,
                              void* d_out, int out_size, void* d_ws,
                              size_t ws_size, hipStream_t stream) {
  const float* x = (const float*)d_in[0];
  const float* ew = (const float*)d_in[1];
  const int* tok = (const int*)d_in[2];
  const float* w1 = (const float*)d_in[3];
  const float* w2 = (const float*)d_in[4];
  const float* w3 = (const float*)d_in[5];
  float* out = (float*)d_out;

  const size_t wE = (size_t)En * Dn * Fn;        // 16.78M elems per weight
  const size_t xgE = (size_t)En * Mn * Dn;       // 33.55M elems
  const size_t hbE = (size_t)(En / 2) * Mn * Fn; // 33.55M elems (half)
  __bf16* w1T = (__bf16*)d_ws;
  __bf16* w2T = w1T + wE;
  __bf16* w3T = w2T + wE;
  __bf16* Xg = w3T + wE;
  __bf16* Hbh = Xg + xgE;
  const size_t need = (3 * wE + xgE + hbE) * sizeof(__bf16); // ~235MB
  if (ws_size < need) return; // fail loudly (output stays poisoned)

  (void)hipMemsetAsync(d_out, 0, (size_t)Bn * Sn * Dn * sizeof(float), stream);

  tcast_kernel<<<dim3(Fn / 32, Dn / 32, En), 256, 0, stream>>>(w1, w1T, Dn, Fn);
  tcast_kernel<<<dim3(Fn / 32, Dn / 32, En), 256, 0, stream>>>(w2, w2T, Dn, Fn);
  tcast_kernel<<<dim3(Dn / 32, Fn / 32, En), 256, 0, stream>>>(w3, w3T, Fn, Dn);
  gather_cast_kernel<<<dim3(En * Mn / 4), 256, 0, stream>>>(x, tok, Xg);
  for (int h = 0; h < 2; ++h) {
    gemm12_kernel<<<dim3(16, 16, En / 2), 512, 0, stream>>>(Xg, ew, w1T, w2T,
                                                            Hbh, h * (En / 2));
    gemm3_kernel<<<dim3(16, 4, En / 2), 512, 0, stream>>>(Hbh, w3T, tok, out,
                                                          h * (En / 2));
  }
}